// Round 1
// baseline (600.105 us; speedup 1.0000x reference)
//
#include <hip/hip_runtime.h>
#include <stdint.h>

#define D_DIM   11008
#define NROWS   8192        // 2*4096
#define KD      172
#define MD      64
#define BPB     8
#define TSTRIDE 200         // bf16 elements per m-row in T_lds (padded from 192)
#define MT_PER_WAVE 3       // 12 M-tiles of 16 rows (192 >= 172), 4 waves

typedef short bf16x8 __attribute__((ext_vector_type(8)));
typedef short bf16x4 __attribute__((ext_vector_type(4)));
typedef float floatx4 __attribute__((ext_vector_type(4)));

__device__ __forceinline__ short f2bf(float f) {
  // round-to-nearest-even fp32 -> bf16
  uint32_t u = __builtin_bit_cast(uint32_t, f);
  u = (u + 0x7FFFu + ((u >> 16) & 1u)) >> 16;
  return (short)u;
}

__global__ __launch_bounds__(256, 2)
void had_kernel(const float* __restrict__ x,
                const float* __restrict__ hadK,
                float* __restrict__ out) {
  __shared__ short T_lds[MD * TSTRIDE];   // 25,600 B: T stored [m][j], bf16

  const int tid  = threadIdx.x;
  const int wave = tid >> 6;
  const int lane = tid & 63;
  const int lq   = lane >> 4;   // quad 0..3
  const int ln   = lane & 15;

  const int mt0 = wave * MT_PER_WAVE;   // first of this wave's 3 M-tiles (of 12)

  // ---- preload had_K A-fragments: A[i][j], bf16, zero for j >= 172, clamp i
  bf16x8 hfrag[MT_PER_WAVE][6];
  for (int m = 0; m < MT_PER_WAVE; ++m) {
    int i = (mt0 + m) * 16 + ln;
    if (i > KD - 1) i = KD - 1;
    const float* rowp = hadK + i * KD;
    for (int ks = 0; ks < 6; ++ks) {
      int j0 = ks * 32 + lq * 8;
      bf16x8 f;
      #pragma unroll
      for (int u = 0; u < 8; ++u) {
        int j = j0 + u;
        float v = (j < KD) ? rowp[j] : 0.0f;
        f[u] = f2bf(v);
      }
      hfrag[m][ks] = f;
    }
  }

  // ---- H64 B-fragments: H64[k][n] = (-1)^popcount(k&n), exact +-1 in bf16
  bf16x8 h64[4][2];
  for (int n = 0; n < 4; ++n) {
    for (int ks = 0; ks < 2; ++ks) {
      bf16x8 f;
      #pragma unroll
      for (int u = 0; u < 8; ++u) {
        int k = ks * 32 + lq * 8 + u;
        int c = n * 16 + ln;
        f[u] = (short)((__builtin_popcount(k & c) & 1) ? 0xBF80 : 0x3F80);
      }
      h64[n][ks] = f;
    }
  }

  const float SCALE = (float)(1.0 / __builtin_sqrt((double)D_DIM));

  for (int bb = 0; bb < BPB; ++bb) {
    const int b = blockIdx.x * BPB + bb;
    const float* xb = x + (size_t)b * D_DIM;
    float*       ob = out + (size_t)b * D_DIM;

    // ---- GEMM-A: T(192x64) = Xpad(192x64) @ H64(64x64), K = 64 (2 steps)
    floatx4 accA[MT_PER_WAVE][4];
    #pragma unroll
    for (int m = 0; m < MT_PER_WAVE; ++m)
      #pragma unroll
      for (int n = 0; n < 4; ++n)
        accA[m][n] = (floatx4){0.f, 0.f, 0.f, 0.f};

    #pragma unroll
    for (int m = 0; m < MT_PER_WAVE; ++m) {
      int j = (mt0 + m) * 16 + ln;           // X row (clamped; pad rows harmless)
      if (j > KD - 1) j = KD - 1;
      const float* rowx = xb + j * MD;
      #pragma unroll
      for (int ks = 0; ks < 2; ++ks) {
        const float4* p = (const float4*)(rowx + ks * 32 + lq * 8);
        float4 v0 = p[0];
        float4 v1 = p[1];
        bf16x8 af;
        af[0] = f2bf(v0.x); af[1] = f2bf(v0.y); af[2] = f2bf(v0.z); af[3] = f2bf(v0.w);
        af[4] = f2bf(v1.x); af[5] = f2bf(v1.y); af[6] = f2bf(v1.z); af[7] = f2bf(v1.w);
        #pragma unroll
        for (int n = 0; n < 4; ++n)
          accA[m][n] = __builtin_amdgcn_mfma_f32_16x16x32_bf16(
              af, h64[n][ks], accA[m][n], 0, 0, 0);
      }
    }

    // ---- write T to LDS (bf16): lane holds T[j0+4q+r][col], 4 consecutive j
    #pragma unroll
    for (int m = 0; m < MT_PER_WAVE; ++m) {
      int j0 = (mt0 + m) * 16 + lq * 4;
      #pragma unroll
      for (int n = 0; n < 4; ++n) {
        int col = n * 16 + ln;
        bf16x4 t;
        t[0] = f2bf(accA[m][n][0]);
        t[1] = f2bf(accA[m][n][1]);
        t[2] = f2bf(accA[m][n][2]);
        t[3] = f2bf(accA[m][n][3]);
        *(bf16x4*)&T_lds[col * TSTRIDE + j0] = t;
      }
    }
    __syncthreads();

    // ---- GEMM-B: OUT(192x64) = HADpad(192x192) @ T(192x64), K = 192 (6 steps)
    floatx4 accB[MT_PER_WAVE][4];
    #pragma unroll
    for (int m = 0; m < MT_PER_WAVE; ++m)
      #pragma unroll
      for (int n = 0; n < 4; ++n)
        accB[m][n] = (floatx4){0.f, 0.f, 0.f, 0.f};

    for (int ks = 0; ks < 6; ++ks) {
      #pragma unroll
      for (int n = 0; n < 4; ++n) {
        bf16x8 bf = *(const bf16x8*)&T_lds[(n * 16 + ln) * TSTRIDE + ks * 32 + lq * 8];
        #pragma unroll
        for (int m = 0; m < MT_PER_WAVE; ++m)
          accB[m][n] = __builtin_amdgcn_mfma_f32_16x16x32_bf16(
              hfrag[m][ks], bf, accB[m][n], 0, 0, 0);
      }
    }

    // ---- epilogue: out[b][i][m] = acc * scale, mask i >= 172
    #pragma unroll
    for (int m = 0; m < MT_PER_WAVE; ++m) {
      int i0 = (mt0 + m) * 16 + lq * 4;
      #pragma unroll
      for (int n = 0; n < 4; ++n) {
        int col = n * 16 + ln;
        #pragma unroll
        for (int r = 0; r < 4; ++r) {
          int i = i0 + r;
          if (i < KD) ob[i * MD + col] = accB[m][n][r] * SCALE;
        }
      }
    }
    __syncthreads();   // protect T_lds before next b overwrites
  }
}

extern "C" void kernel_launch(void* const* d_in, const int* in_sizes, int n_in,
                              void* d_out, int out_size, void* d_ws, size_t ws_size,
                              hipStream_t stream) {
  const float* x    = (const float*)d_in[0];
  const float* hadK = (const float*)d_in[1];
  float* out        = (float*)d_out;
  had_kernel<<<dim3(NROWS / BPB), dim3(256), 0, stream>>>(x, hadK, out);
}